// Round 7
// baseline (16.759 us; speedup 1.0000x reference)
//
#include <hip/hip_runtime.h>

// 3x3 median blur, BORDER_REPLICATE, NHWC float32. B=64, H=224, W=224, C=3.
// R3: vertical 4-row coarsening (6 rows loaded per 4 output rows).
// R2: chunked XCD swizzle (grid 2352 = 8 * 294; band = 8 whole images).
// R5: nontemporal stores (output never re-read; keep write stream out of L2).
// R6: nontemporal loads for the read-once interior rows (r=2,3 -> h===1,2
//     mod 4). Rows h===0,3 mod 4 are read twice (own group + neighbor halo);
//     keeping ONLY those in L2 shrinks the in-flight read working set per
//     XCD from ~4.8 MB (>4 MiB L2) to ~2.4 MB, so the second touch hits L2
//     instead of re-fetching from HBM.

typedef float f32x4 __attribute__((ext_vector_type(4)));

__device__ __forceinline__ float min3f(float a, float b, float c) {
    return fminf(fminf(a, b), c);           // v_min3_f32
}
__device__ __forceinline__ float max3f(float a, float b, float c) {
    return fmaxf(fmaxf(a, b), c);           // v_max3_f32
}
__device__ __forceinline__ float med3f(float a, float b, float c) {
    return __builtin_amdgcn_fmed3f(a, b, c); // v_med3_f32
}

__global__ __launch_bounds__(256) void median3x3_r6(
    const float* __restrict__ in, float* __restrict__ out)
{
    const int W = 224, H = 224;
    const int ROWF   = W * 3;      // 672 floats per row
    const int CHUNKS = ROWF / 4;   // 168 float4 chunks per row
    const int GROUPS = H / 4;      // 56 row-groups per image
    const int NXCD   = 8;
    const int BAND   = 2352 / NXCD; // 294 blocks per XCD band

    int bid  = blockIdx.x;
    int virt = (bid & (NXCD - 1)) * BAND + (bid >> 3);

    int t    = virt * 256 + threadIdx.x;
    int ci   = t % CHUNKS;
    int rest = t / CHUNKS;
    int g    = rest % GROUPS;      // row group within image
    int b    = rest / GROUPS;      // image index
    int r0   = g * 4;              // first output row of this thread

    const float* img = in + (size_t)b * H * ROWF;

    const int li  = (ci > 0)          ? ci - 1 : 0;
    const int riq = (ci < CHUNKS - 1) ? ci + 1 : CHUNKS - 1;
    const bool first = (ci == 0), last = (ci == CHUNKS - 1);

    // v[r][q]: input row (r0 + r - 1, clamped) at chunk-relative float
    // position q-3 (q = 0..9 -> -3..6)
    float v[6][10];
    #pragma unroll
    for (int r = 0; r < 6; ++r) {
        int h = r0 + r - 1;
        h = (h < 0) ? 0 : ((h > H - 1) ? H - 1 : h);
        const f32x4* rp = (const f32x4*)(img + (size_t)h * ROWF);
        // r=2,3 -> h===1,2 (mod 4): read exactly once globally -> nontemporal.
        // r=0,1,4,5 -> h===0,3 (mod 4): read twice (halo) -> keep in L2.
        const bool nt = (r == 2) || (r == 3);   // compile-time after unroll
        f32x4 L = nt ? __builtin_nontemporal_load(rp + li)  : rp[li];
        f32x4 M = nt ? __builtin_nontemporal_load(rp + ci)  : rp[ci];
        f32x4 R = nt ? __builtin_nontemporal_load(rp + riq) : rp[riq];
        v[r][0] = first ? M.x : L.y;   // pos -3
        v[r][1] = first ? M.y : L.z;   // pos -2
        v[r][2] = first ? M.z : L.w;   // pos -1
        v[r][3] = M.x;
        v[r][4] = M.y;
        v[r][5] = M.z;
        v[r][6] = M.w;
        v[r][7] = last ? M.y : R.x;    // pos 4
        v[r][8] = last ? M.z : R.y;    // pos 5
        v[r][9] = last ? M.w : R.z;    // pos 6
    }

    float* oimg = out + (size_t)b * H * ROWF;

    #pragma unroll
    for (int k = 0; k < 4; ++k) {      // output row r0 + k uses v[k..k+2]
        float lo[10], me[10], hi[10];
        #pragma unroll
        for (int q = 0; q < 10; ++q) {
            lo[q] = min3f(v[k][q], v[k + 1][q], v[k + 2][q]);
            me[q] = med3f(v[k][q], v[k + 1][q], v[k + 2][q]);
            hi[q] = max3f(v[k][q], v[k + 1][q], v[k + 2][q]);
        }
        f32x4 o;
        o.x = med3f(max3f(lo[0], lo[3], lo[6]),
                    med3f(me[0], me[3], me[6]),
                    min3f(hi[0], hi[3], hi[6]));
        o.y = med3f(max3f(lo[1], lo[4], lo[7]),
                    med3f(me[1], me[4], me[7]),
                    min3f(hi[1], hi[4], hi[7]));
        o.z = med3f(max3f(lo[2], lo[5], lo[8]),
                    med3f(me[2], me[5], me[8]),
                    min3f(hi[2], hi[5], hi[8]));
        o.w = med3f(max3f(lo[3], lo[6], lo[9]),
                    med3f(me[3], me[6], me[9]),
                    min3f(hi[3], hi[6], hi[9]));
        f32x4* dst = (f32x4*)(oimg + (size_t)(r0 + k) * ROWF) + ci;
        __builtin_nontemporal_store(o, dst);
    }
}

extern "C" void kernel_launch(void* const* d_in, const int* in_sizes, int n_in,
                              void* d_out, int out_size, void* d_ws, size_t ws_size,
                              hipStream_t stream) {
    const float* x = (const float*)d_in[0];
    float* out     = (float*)d_out;

    // total threads = 64 * 56 * 168 = 602,112 = 2352 blocks * 256 (exact)
    const int grid  = 2352;
    const int block = 256;
    median3x3_r6<<<grid, block, 0, stream>>>(x, out);
}